// Round 18
// baseline (247.278 us; speedup 1.0000x reference)
//
#include <hip/hip_runtime.h>
#include <hip/hip_bf16.h>
#include <cstddef>

#define DMODEL 1024
#define DI     2048
#define DS     16
#define LSEQ   2048
#define BATCH  2
#define NC     128           // number of scan chunks
#define TCH    (LSEQ / NC)   // 16 steps per chunk

typedef __attribute__((ext_vector_type(8))) short short8;
typedef __attribute__((ext_vector_type(4))) float f32x4;
typedef __attribute__((ext_vector_type(2))) float f32x2;
typedef __attribute__((ext_vector_type(8))) unsigned short us8;

__device__ __forceinline__ unsigned short f2bf(float f) {
    unsigned int u = __float_as_uint(f);
    unsigned int r = (u + 0x7fff + ((u >> 16) & 1)) >> 16;   // RNE
    return (unsigned short)r;
}
__device__ __forceinline__ float bf2f(unsigned short b) {
    return __uint_as_float(((unsigned int)b) << 16);
}

__device__ __forceinline__ float fexp2(float x) {
#if __has_builtin(__builtin_amdgcn_exp2f)
    return __builtin_amdgcn_exp2f(x);
#else
    return exp2f(x);
#endif
}
__device__ __forceinline__ float flog2(float x) {
#if __has_builtin(__builtin_amdgcn_logf)
    return __builtin_amdgcn_logf(x);
#else
    return log2f(x);
#endif
}

#define LOG2E 1.4426950408889634f
#define RLOG2E 0.6931471805599453f

__device__ __forceinline__ float softplus_f(float v) {
    return (v > 20.f) ? v : flog2(1.f + fexp2(v * LOG2E)) * RLOG2E;
}

__device__ __forceinline__ void gload_lds16(const void* g, void* l) {
    __builtin_amdgcn_global_load_lds(
        (const __attribute__((address_space(1))) unsigned int*)g,
        (__attribute__((address_space(3))) unsigned int*)l, 16, 0, 0);
}

__device__ __forceinline__ void cvt8_store(const float* __restrict__ in,
                                           unsigned short* __restrict__ out, int i) {
    const float4* p = reinterpret_cast<const float4*>(in) + (size_t)i * 2;
    float4 v0 = p[0], v1 = p[1];
    us8 o;
    o[0] = f2bf(v0.x); o[1] = f2bf(v0.y); o[2] = f2bf(v0.z); o[3] = f2bf(v0.w);
    o[4] = f2bf(v1.x); o[5] = f2bf(v1.y); o[6] = f2bf(v1.z); o[7] = f2bf(v1.w);
    *reinterpret_cast<us8*>(out + (size_t)i * 8) = o;
}

// ---------------------------------------------------------------------------
// fused prep: cvt x, W_in, W_out; pad+cvt W_x; A-table  (one launch)
// ---------------------------------------------------------------------------
#define PREP_X   524288
#define PREP_WI  (PREP_X + 524288)
#define PREP_WO  (PREP_WI + 262144)
#define PREP_WX  (PREP_WO + 12288)
#define PREP_A   (PREP_WX + 32768)
__global__ void prep_all(const float* __restrict__ x, const float* __restrict__ W_in,
                         const float* __restrict__ W_out, const float* __restrict__ wx,
                         const float* __restrict__ A_log,
                         unsigned short* __restrict__ Xb, unsigned short* __restrict__ W_inb,
                         unsigned short* __restrict__ W_outb, unsigned short* __restrict__ Wxb48,
                         float* __restrict__ At2) {
    int i = blockIdx.x * 256 + threadIdx.x;
    if (i < PREP_X) {
        cvt8_store(x, Xb, i);
    } else if (i < PREP_WI) {
        cvt8_store(W_in, W_inb, i - PREP_X);
    } else if (i < PREP_WO) {
        cvt8_store(W_out, W_outb, i - PREP_WI);
    } else if (i < PREP_WX) {
        int j = i - PREP_WO;
        size_t o = (size_t)j * 8;
        int row = (int)(o >> 11);
        if (row < 33) cvt8_store(wx, Wxb48, j);
        else *reinterpret_cast<us8*>(Wxb48 + o) = (us8)0;
    } else if (i < PREP_A) {
        int j = i - PREP_WX;            // j = n*DI + d
        int n = j / DI, d = j % DI;
        At2[j] = -__expf(A_log[d * DS + n]) * LOG2E;
    }
}

// ---------------------------------------------------------------------------
// GEMM1 (best measured variant, R9): 128x256 tile, 8 waves (2Mx4N, wave owns
// 64x64), BK=32, 2-deep LDS dbuf (48 KiB -> 2 blocks/CU, 16 waves/CU),
// XOR swizzle, setprio, bf16 out.  M=4096, N=4096, K=1024; grid 512.
// ---------------------------------------------------------------------------
#define NTK1 32
__global__ __launch_bounds__(512, 4)
void gemm1_2b(const unsigned short* __restrict__ A, const unsigned short* __restrict__ B,
              unsigned short* __restrict__ C) {
    __shared__ unsigned short As[2][128 * 32];   // 2 x 8 KiB
    __shared__ unsigned short Bs[2][256 * 32];   // 2 x 16 KiB

    const int tid = threadIdx.x;
    const int wid = tid >> 6, ln = tid & 63;
    const int wm = wid >> 2, wn = wid & 3;       // wave owns 64x64

    int wg = blockIdx.x;
    wg = (wg & 7) * 64 + (wg >> 3);              // XCD swizzle (512 % 8 == 0)
    const int m0 = (wg >> 4) * 128;
    const int n0 = (wg & 15) * 256;

    const int srow = tid >> 2;                   // 0..127
    const int sun  = tid & 3;
    const int ksrc = ((sun ^ ((srow >> 1) & 3)) * 8);  // same for srow and srow+128

    const int fr = ln & 15;
    const int fku = (ln >> 4);

    f32x4 acc[4][4] = {};

    #define STAGE1(kt, c)                                                                  \
        do {                                                                               \
            gload_lds16(A + (size_t)(m0 + srow) * 1024 + (kt) * 32 + ksrc,                 \
                        &As[c][srow * 32 + sun * 8]);                                      \
            gload_lds16(B + (size_t)(n0 + srow) * 1024 + (kt) * 32 + ksrc,                 \
                        &Bs[c][srow * 32 + sun * 8]);                                      \
            gload_lds16(B + (size_t)(n0 + 128 + srow) * 1024 + (kt) * 32 + ksrc,           \
                        &Bs[c][(128 + srow) * 32 + sun * 8]);                              \
        } while (0)

    STAGE1(0, 0);
    asm volatile("s_waitcnt vmcnt(0)" ::: "memory");
    __builtin_amdgcn_s_barrier();
    __builtin_amdgcn_sched_barrier(0);

    for (int kt = 0; kt < NTK1; ++kt) {
        const int c = kt & 1;
        if (kt + 1 < NTK1) STAGE1(kt + 1, c ^ 1);   // c^1 fully consumed before last barrier

        short8 af[4], bfr[4];
        #pragma unroll
        for (int i = 0; i < 4; ++i) {
            int r = wm * 64 + i * 16 + fr;
            int u = fku ^ ((r >> 1) & 3);
            af[i] = *reinterpret_cast<const short8*>(&As[c][r * 32 + u * 8]);
        }
        #pragma unroll
        for (int j = 0; j < 4; ++j) {
            int r = wn * 64 + j * 16 + fr;
            int u = fku ^ ((r >> 1) & 3);
            bfr[j] = *reinterpret_cast<const short8*>(&Bs[c][r * 32 + u * 8]);
        }
        __builtin_amdgcn_sched_barrier(0);
        __builtin_amdgcn_s_setprio(1);
        #pragma unroll
        for (int i = 0; i < 4; ++i)
            #pragma unroll
            for (int j = 0; j < 4; ++j)
                acc[i][j] = __builtin_amdgcn_mfma_f32_16x16x32_bf16(af[i], bfr[j], acc[i][j], 0, 0, 0);
        __builtin_amdgcn_s_setprio(0);
        __builtin_amdgcn_sched_barrier(0);

        if (kt + 1 < NTK1) asm volatile("s_waitcnt vmcnt(0)" ::: "memory");
        __builtin_amdgcn_s_barrier();
        __builtin_amdgcn_sched_barrier(0);
    }
    #undef STAGE1

    const int cr = (ln >> 4) * 4, cc = ln & 15;
    #pragma unroll
    for (int i = 0; i < 4; ++i) {
        int row = m0 + wm * 64 + i * 16 + cr;
        #pragma unroll
        for (int j = 0; j < 4; ++j) {
            int col = n0 + wn * 64 + j * 16 + cc;
            #pragma unroll
            for (int r = 0; r < 4; ++r)
                C[(size_t)(row + r) * 4096 + col] = f2bf(acc[i][j][r]);
        }
    }
}

// ---------------------------------------------------------------------------
// GEMM3: 128x64 tile, 4 waves (2x2), BK=32, 4-deep pipeline, counted vmcnt,
// k-unit XOR swizzle, f32 out.  A dense lda=2048.  grid 512.
// ---------------------------------------------------------------------------
#define NT3 64
__global__ __launch_bounds__(256, 2)
void gemm3_pipe(const unsigned short* __restrict__ A,
                const unsigned short* __restrict__ B,
                float* __restrict__ C) {
    __shared__ unsigned short As[4][128 * 32];   // 32 KiB
    __shared__ unsigned short Bs[4][64 * 32];    // 16 KiB

    const int tid = threadIdx.x;
    const int wid = tid >> 6, ln = tid & 63;
    const int wm = wid >> 1, wn = wid & 1;       // wave owns 64x32

    int wg = blockIdx.x;
    wg = (wg & 7) * 64 + (wg >> 3);              // XCD swizzle (512 % 8 == 0)
    const int m0 = (wg >> 4) * 128;
    const int n0 = (wg & 15) * 64;

    const int srow = tid >> 2;                   // 0..63
    const int sun  = tid & 3;
    const int ksrc = ((sun ^ ((srow >> 1) & 3)) * 8);

    const int fr = ln & 15;
    const int fku = (ln >> 4);

    f32x4 acc[4][2] = {};

    #define STAGE3(kt)                                                                     \
        do {                                                                               \
            const int bq_ = (kt) & 3;                                                      \
            gload_lds16(A + (size_t)(m0 + srow) * 2048 + (kt) * 32 + ksrc,                 \
                        &As[bq_][srow * 32 + sun * 8]);                                    \
            gload_lds16(A + (size_t)(m0 + 64 + srow) * 2048 + (kt) * 32 + ksrc,            \
                        &As[bq_][(64 + srow) * 32 + sun * 8]);                             \
            gload_lds16(B + (size_t)(n0 + srow) * 2048 + (kt) * 32 + ksrc,                 \
                        &Bs[bq_][srow * 32 + sun * 8]);                                    \
        } while (0)

    STAGE3(0); STAGE3(1); STAGE3(2);
    asm volatile("s_waitcnt vmcnt(6)" ::: "memory");   // K-tile 0 landed
    __builtin_amdgcn_s_barrier();
    __builtin_amdgcn_sched_barrier(0);

    for (int kt = 0; kt < NT3; ++kt) {
        const int bq = kt & 3;
        if (kt + 3 < NT3) STAGE3(kt + 3);

        short8 af[4], bfr[2];
        #pragma unroll
        for (int i = 0; i < 4; ++i) {
            int r = wm * 64 + i * 16 + fr;
            int u = fku ^ ((r >> 1) & 3);
            af[i] = *reinterpret_cast<const short8*>(&As[bq][r * 32 + u * 8]);
        }
        #pragma unroll
        for (int j = 0; j < 2; ++j) {
            int r = wn * 32 + j * 16 + fr;
            int u = fku ^ ((r >> 1) & 3);
            bfr[j] = *reinterpret_cast<const short8*>(&Bs[bq][r * 32 + u * 8]);
        }
        __builtin_amdgcn_sched_barrier(0);
        __builtin_amdgcn_s_setprio(1);
        #pragma unroll
        for (int i = 0; i < 4; ++i)
            #pragma unroll
            for (int j = 0; j < 2; ++j)
                acc[i][j] = __builtin_amdgcn_mfma_f32_16x16x32_bf16(af[i], bfr[j], acc[i][j], 0, 0, 0);
        __builtin_amdgcn_s_setprio(0);
        __builtin_amdgcn_sched_barrier(0);

        if (kt < NT3 - 3)       asm volatile("s_waitcnt vmcnt(6)" ::: "memory");
        else if (kt == NT3 - 3) asm volatile("s_waitcnt vmcnt(3)" ::: "memory");
        else if (kt == NT3 - 2) asm volatile("s_waitcnt vmcnt(0)" ::: "memory");
        __builtin_amdgcn_s_barrier();
        __builtin_amdgcn_sched_barrier(0);
    }
    #undef STAGE3

    const int cr = (ln >> 4) * 4, cc = ln & 15;
    #pragma unroll
    for (int i = 0; i < 4; ++i) {
        int row = m0 + wm * 64 + i * 16 + cr;
        #pragma unroll
        for (int j = 0; j < 2; ++j) {
            int col = n0 + wn * 32 + j * 16 + cc;
            #pragma unroll
            for (int r = 0; r < 4; ++r)
                C[(size_t)(row + r) * 1024 + col] = acc[i][j][r];
        }
    }
}

// ---------------------------------------------------------------------------
// FUSED conv+proj, K split 16 ways (grid (64,16) = 1024 blocks, 4 blocks/CU).
// ---------------------------------------------------------------------------
#define RAWS 40   // padded LDS row stride (elements)
__global__ __launch_bounds__(256)
void gemm_proj_conv(const unsigned short* __restrict__ XZb, const unsigned short* __restrict__ Wxb,
                    const float* __restrict__ cw, const float* __restrict__ cb,
                    float* __restrict__ projp) {
    __shared__ unsigned short raw[67 * RAWS];    // xz window rows m0-3..m0+63
    __shared__ unsigned short Bs[48 * 32];

    const int tid = threadIdx.x;
    const int wv = tid >> 6, ln = tid & 63;
    const int m0 = blockIdx.x * 64;
    const int kz = blockIdx.y;                   // 0..15
    const int srow = tid >> 2, skoff = (tid & 3) * 8;
    const int fr = ln & 15;
    const int lhat = wv * 16 + fr;               // output row 0..63
    const int d0 = (ln >> 4) * 8;                // fragment k-offset 0/8/16/24

    const bool mstart = ((m0 & 2047) == 0);      // block at batch start
    const int colbase = kz * 128;

    f32x4 acc[3] = {};

    for (int k0 = 0; k0 < 128; k0 += 32) {
        for (int j = tid; j < 268; j += 256) {
            int i = j >> 2, slot = j & 3;
            us8 v;
            if (mstart && i < 3) {
                v = (us8)0;
            } else {
                v = *reinterpret_cast<const us8*>(
                    XZb + (size_t)(m0 - 3 + i) * 4096 + colbase + k0 + slot * 8);
            }
            *reinterpret_cast<us8*>(&raw[i * RAWS + slot * 8]) = v;
        }
        if (wv < 3)
            gload_lds16(Wxb + (size_t)srow * 2048 + colbase + k0 + skoff, &Bs[wv * 512]);
        __syncthreads();

        short8 af;
        #pragma unroll
        for (int e = 0; e < 8; ++e) {
            int dg = colbase + k0 + d0 + e;
            float a = cb[dg];
            float4 w = *reinterpret_cast<const float4*>(cw + dg * 4);
            a += bf2f(raw[(lhat + 0) * RAWS + d0 + e]) * w.x;
            a += bf2f(raw[(lhat + 1) * RAWS + d0 + e]) * w.y;
            a += bf2f(raw[(lhat + 2) * RAWS + d0 + e]) * w.z;
            a += bf2f(raw[(lhat + 3) * RAWS + d0 + e]) * w.w;
            float v = a / (1.f + __expf(-a));
            ((unsigned short*)&af)[e] = (short)f2bf(v);
        }

        #pragma unroll
        for (int j = 0; j < 3; ++j) {
            short8 bf_ = *reinterpret_cast<const short8*>(&Bs[(j * 16 + fr) * 32 + d0]);
            acc[j] = __builtin_amdgcn_mfma_f32_16x16x32_bf16(af, bf_, acc[j], 0, 0, 0);
        }
        __syncthreads();
    }

    const int cr = (ln >> 4) * 4, cc = ln & 15;
    #pragma unroll
    for (int j = 0; j < 3; ++j) {
        int col = j * 16 + cc;
        if (col < 33) {
            #pragma unroll
            for (int r = 0; r < 4; ++r) {
                int row = m0 + wv * 16 + cr + r;
                projp[(size_t)row * 576 + kz * 36 + col] = acc[j][r];
            }
        }
    }
}

// combine 16 K-split partials -> dense PROJ[row*36+col]
__global__ void proj_combine(const float* __restrict__ projp, float* __restrict__ proj) {
    int idx = blockIdx.x * 256 + threadIdx.x;
    if (idx >= BATCH * LSEQ * 33) return;
    int row = idx / 33, col = idx % 33;
    const float* pp = projp + (size_t)row * 576 + col;
    float s = 0.f;
    #pragma unroll
    for (int kz = 0; kz < 16; ++kz)
        s += pp[kz * 36];
    proj[(size_t)row * 36 + col] = s;
}

// ---------------------------------------------------------------------------
// scan phase 1: local scan (h0=0) with in-register conv recompute from XZb.
// y_local + x*D (bf16), Hend (bf16), dtsum (f32).
// ---------------------------------------------------------------------------
__global__ __launch_bounds__(256)
void scan_phase1(const unsigned short* __restrict__ XZb, const float* __restrict__ proj,
                 const float* __restrict__ At2, const float* __restrict__ W_dt,
                 const float* __restrict__ b_dt, const float* __restrict__ Dp,
                 const float* __restrict__ cw, const float* __restrict__ cb,
                 unsigned short* __restrict__ Hend,
                 float* __restrict__ dtsum, unsigned short* __restrict__ yloc) {
    const int d = blockIdx.x * 256 + threadIdx.x;
    const int c = blockIdx.y;
    const int b = blockIdx.z;
    const size_t r0 = (size_t)(b * LSEQ + c * TCH);

    f32x2 A2[DS / 2], h2[DS / 2];
    #pragma unroll
    for (int p = 0; p < DS / 2; ++p) {
        A2[p] = (f32x2){At2[(2 * p) * DI + d], At2[(2 * p + 1) * DI + d]};
        h2[p] = (f32x2){0.f, 0.f};
    }
    const float wdt = W_dt[d], bdt = b_dt[d], Dv = Dp[d];
    const float4 w = *reinterpret_cast<const float4*>(cw + d * 4);
    const float cbv = cb[d];

    float r3, r2, r1;
    if (c == 0) {
        r3 = r2 = r1 = 0.f;
    } else {
        r3 = bf2f(XZb[(r0 - 3) * 4096 + d]);
        r2 = bf2f(XZb[(r0 - 2) * 4096 + d]);
        r1 = bf2f(XZb[(r0 - 1) * 4096 + d]);
    }
    float ssum = 0.f;

    #pragma unroll 2
    for (int rl = 0; rl < TCH; ++rl) {
        const size_t row = r0 + rl;
        const float* pr = proj + row * 36;
        float dt = softplus_f(pr[32] * wdt + bdt);
        ssum += dt;
        float rr = bf2f(XZb[row * 4096 + d]);
        float a = cbv + r3 * w.x + r2 * w.y + r1 * w.z + rr * w.w;
        r3 = r2; r2 = r1; r1 = rr;
        float v = a / (1.f + __expf(-a));
        float x = bf2f(f2bf(v));                 // match proj_conv's bf16 rounding
        float xdt = x * dt;
        f32x2 xdt2 = (f32x2){xdt, xdt};
        f32x2 y2 = (f32x2){0.f, 0.f};
        #pragma unroll
        for (int p = 0; p < DS / 2; ++p) {
            f32x2 t = A2[p] * dt;
            f32x2 e2 = (f32x2){fexp2(t.x), fexp2(t.y)};
            h2[p] = e2 * h2[p] + xdt2 * (f32x2){pr[2 * p], pr[2 * p + 1]};
            y2 += h2[p] * (f32x2){pr[16 + 2 * p], pr[17 + 2 * p]};
        }
        yloc[row * DI + d] = f2bf(y2.x + y2.y + x * Dv);   // x*D folded in
    }
    size_t base = ((size_t)(b * NC + c) * DS) * DI + d;
    #pragma unroll
    for (int p = 0; p < DS / 2; ++p) {
        Hend[base + (size_t)(2 * p) * DI]     = f2bf(h2[p].x);
        Hend[base + (size_t)(2 * p + 1) * DI] = f2bf(h2[p].y);
    }
    dtsum[(size_t)(b * NC + c) * DI + d] = ssum;
}

// ---------------------------------------------------------------------------
// scan phase 2: WAVE-PARALLEL affine scan.  One wave per (b,n,d); lanes hold
// chunks (ln, 64+ln); Hillis-Steele inclusive shuffle-scan of (P,H) affine
// maps, exclusive shift -> Hin; lane-63 total carries seg0 into seg1.
// Grid 16384 x 256 (full occupancy vs 256-block serial version).
// ---------------------------------------------------------------------------
__global__ __launch_bounds__(256)
void scan_phase2(unsigned short* __restrict__ H, const float* __restrict__ dtsum,
                 const float* __restrict__ At2) {
    const int tid = threadIdx.x;
    const int ln = tid & 63;
    const int widx = blockIdx.x * 4 + (tid >> 6);   // wave id = (b,n,d) triple
    const int b = widx / (DS * DI);
    const int r = widx % (DS * DI);
    const int n = r / DI, d = r % DI;
    const float A2 = At2[n * DI + d];

    // segment 0: chunk c0 = ln;  segment 1: chunk c1 = 64 + ln
    const size_t off0 = ((size_t)(b * NC + ln) * DS + n) * DI + d;
    const size_t off1 = ((size_t)(b * NC + 64 + ln) * DS + n) * DI + d;
    float He0 = bf2f(H[off0]);
    float He1 = bf2f(H[off1]);
    float P0 = fexp2(A2 * dtsum[(size_t)(b * NC + ln) * DI + d]);
    float P1 = fexp2(A2 * dtsum[(size_t)(b * NC + 64 + ln) * DI + d]);

    // inclusive Hillis-Steele scan of affine maps (apply-after composition)
    #pragma unroll
    for (int s = 1; s < 64; s <<= 1) {
        float Pp0 = __shfl_up(P0, s), Hp0 = __shfl_up(He0, s);
        float Pp1 = __shfl_up(P1, s), Hp1 = __shfl_up(He1, s);
        if (ln >= s) {
            He0 = P0 * Hp0 + He0;  P0 = P0 * Pp0;
            He1 = P1 * Hp1 + He1;  P1 = P1 * Pp1;
        }
    }
    // seg0 total (chunks 0..63)
    float Ht0 = __shfl(He0, 63);

    // exclusive shift -> Hin
    float hin0 = __shfl_up(He0, 1);
    if (ln == 0) hin0 = 0.f;
    float Pex1 = __shfl_up(P1, 1), Hex1 = __shfl_up(He1, 1);
    if (ln == 0) { Pex1 = 1.f; Hex1 = 0.f; }
    float hin1 = Pex1 * Ht0 + Hex1;

    H[off0] = f2bf(hin0);
    H[off1] = f2bf(hin1);
}

// ---------------------------------------------------------------------------
// scan phase 3: parallel correction + gate; direct proj reads; recomputes
// dt/S in f32.  Writes y (bf16) densely into YB2.
// ---------------------------------------------------------------------------
__global__ __launch_bounds__(256)
void scan_phase3(const unsigned short* __restrict__ yloc,
                 const float* __restrict__ proj, const float* __restrict__ At2,
                 const float* __restrict__ W_dt, const float* __restrict__ b_dt,
                 const unsigned short* __restrict__ Hin,
                 const unsigned short* __restrict__ XZb,
                 unsigned short* __restrict__ YB2) {
    const int tid = threadIdx.x;
    const int d = blockIdx.x * 256 + tid;
    const int c = blockIdx.y;
    const int b = blockIdx.z;
    const size_t r0 = (size_t)(b * LSEQ + c * TCH);

    f32x2 A2[DS / 2], Hn2[DS / 2];
    size_t hbase = ((size_t)(b * NC + c) * DS) * DI + d;
    #pragma unroll
    for (int p = 0; p < DS / 2; ++p) {
        A2[p]  = (f32x2){At2[(2 * p) * DI + d], At2[(2 * p + 1) * DI + d]};
        Hn2[p] = (f32x2){bf2f(Hin[hbase + (size_t)(2 * p) * DI]),
                         bf2f(Hin[hbase + (size_t)(2 * p + 1) * DI])};
    }
    const float wdt = W_dt[d], bdt = b_dt[d];
    float S = 0.f;

    #pragma unroll 2
    for (int rl = 0; rl < TCH; ++rl) {
        const size_t row = r0 + rl;
        const float* pr = proj + row * 36;
        float dt = softplus_f(pr[32] * wdt + bdt);
        S += dt;
        float yl = bf2f(yloc[row * DI + d]);
        float z  = bf2f(XZb[row * 4096 + 2048 + d]);
        f32x2 corr2 = (f32x2){0.f, 0.f};
        #pragma unroll
        for (int p = 0; p < DS / 2; ++p) {
            f32x2 t = A2[p] * S;
            f32x2 e2 = (f32x2){fexp2(t.x), fexp2(t.y)};
            corr2 += (f32x2){pr[16 + 2 * p], pr[17 + 2 * p]} * e2 * Hn2[p];
        }
        float y = yl + corr2.x + corr2.y;
        float sz = z / (1.f + __expf(-z));
        YB2[row * DI + d] = f2bf(y * sz);
    }
}

// ---------------------------------------------------------------------------
extern "C" void kernel_launch(void* const* d_in, const int* in_sizes, int n_in,
                              void* d_out, int out_size, void* d_ws, size_t ws_size,
                              hipStream_t stream) {
    const float* x      = (const float*)d_in[0];
    const float* W_in   = (const float*)d_in[1];
    const float* conv_w = (const float*)d_in[2];
    const float* conv_b = (const float*)d_in[3];
    const float* W_x    = (const float*)d_in[4];
    const float* A_log  = (const float*)d_in[5];
    const float* Dp     = (const float*)d_in[6];
    const float* W_dt   = (const float*)d_in[7];
    const float* b_dt   = (const float*)d_in[8];
    const float* W_out  = (const float*)d_in[9];
    float* out = (float*)d_out;

    char* ws = (char*)d_ws;
    // workspace layout (bytes), ~112 MiB:
    unsigned short* XZb   = (unsigned short*)(ws + 0);           // 32 MiB  [t1..t6]
    float* PROJP = (float*)(ws + 33554432);                      // 9.4 MiB [t2..t2.5]
    unsigned short* Xb    = (unsigned short*)(ws + 50331648);    // 8 MiB   [t0..t1]
    unsigned short* W_inb = (unsigned short*)(ws + 58720256);    // 8 MiB   [t0..t1]
    unsigned short* YB2   = (unsigned short*)(ws + 50331648);    // 16 MiB  [t6..t7] over Xb+W_inb
    unsigned short* Hbuf  = (unsigned short*)(ws + 67108864);    // 16 MiB  [t4..t6]
    unsigned short* YLOC  = (unsigned short*)(ws + 83886080);    // 16 MiB  [t4..t6]
    float* PROJ  = (float*)(ws + 100663296);                     // 0.56 MiB [t2.5..t6]
    float* DTSUM = (float*)(ws + 101711872);                     // 2 MiB
    float* Abuf  = (float*)(ws + 106954752);                     // 128 KiB
    unsigned short* W_outb = (unsigned short*)(ws + 108003328);  // 4 MiB
    unsigned short* Wxb48  = (unsigned short*)(ws + 112197632);  // 192 KiB

    const int M = BATCH * LSEQ;   // 4096

    // t0) fused converts / prep (one launch)
    prep_all<<<(PREP_A + 255) / 256, 256, 0, stream>>>(
        x, W_in, W_out, W_x, A_log, Xb, W_inb, W_outb, Wxb48, Abuf);

    // t1) xz = x @ W_in.T -> bf16 XZb
    gemm1_2b<<<512, 512, 0, stream>>>(Xb, W_inb, XZb);

    // t2) fused conv+SiLU+proj (K split 16) -> PROJP; then dense combine
    gemm_proj_conv<<<dim3(M / 64, 16), 256, 0, stream>>>(
        XZb, Wxb48, conv_w, conv_b, PROJP);
    proj_combine<<<(M * 33 + 255) / 256, 256, 0, stream>>>(PROJP, PROJ);

    // t4-t6) chunked scan (phase2 is wave-parallel shuffle-scan)
    scan_phase1<<<dim3(DI / 256, NC, BATCH), 256, 0, stream>>>(
        XZb, PROJ, Abuf, W_dt, b_dt, Dp, conv_w, conv_b, Hbuf, DTSUM, YLOC);
    scan_phase2<<<BATCH * DS * DI / 4, 256, 0, stream>>>(Hbuf, DTSUM, Abuf);
    scan_phase3<<<dim3(DI / 256, NC, BATCH), 256, 0, stream>>>(
        YLOC, PROJ, Abuf, W_dt, b_dt, Hbuf, XZb, YB2);

    // t7) out = y @ W_out.T  (A = YB2 dense lda=2048)
    gemm3_pipe<<<512, 256, 0, stream>>>(YB2, W_outb, out);
}

// Round 19
// 182.596 us; speedup vs baseline: 1.3542x; 1.3542x over previous
//
#include <hip/hip_runtime.h>
#include <hip/hip_bf16.h>
#include <cstddef>

#define DMODEL 1024
#define DI     2048
#define DS     16
#define LSEQ   2048
#define BATCH  2
#define NC     128           // number of scan chunks
#define TCH    (LSEQ / NC)   // 16 steps per chunk

typedef __attribute__((ext_vector_type(8))) short short8;
typedef __attribute__((ext_vector_type(4))) float f32x4;
typedef __attribute__((ext_vector_type(2))) float f32x2;
typedef __attribute__((ext_vector_type(8))) unsigned short us8;

__device__ __forceinline__ unsigned short f2bf(float f) {
    unsigned int u = __float_as_uint(f);
    unsigned int r = (u + 0x7fff + ((u >> 16) & 1)) >> 16;   // RNE
    return (unsigned short)r;
}
__device__ __forceinline__ float bf2f(unsigned short b) {
    return __uint_as_float(((unsigned int)b) << 16);
}

__device__ __forceinline__ float fexp2(float x) {
#if __has_builtin(__builtin_amdgcn_exp2f)
    return __builtin_amdgcn_exp2f(x);
#else
    return exp2f(x);
#endif
}
__device__ __forceinline__ float flog2(float x) {
#if __has_builtin(__builtin_amdgcn_logf)
    return __builtin_amdgcn_logf(x);
#else
    return log2f(x);
#endif
}

#define LOG2E 1.4426950408889634f
#define RLOG2E 0.6931471805599453f

__device__ __forceinline__ float softplus_f(float v) {
    return (v > 20.f) ? v : flog2(1.f + fexp2(v * LOG2E)) * RLOG2E;
}

__device__ __forceinline__ void gload_lds16(const void* g, void* l) {
    __builtin_amdgcn_global_load_lds(
        (const __attribute__((address_space(1))) unsigned int*)g,
        (__attribute__((address_space(3))) unsigned int*)l, 16, 0, 0);
}

__device__ __forceinline__ void cvt8_store(const float* __restrict__ in,
                                           unsigned short* __restrict__ out, int i) {
    const float4* p = reinterpret_cast<const float4*>(in) + (size_t)i * 2;
    float4 v0 = p[0], v1 = p[1];
    us8 o;
    o[0] = f2bf(v0.x); o[1] = f2bf(v0.y); o[2] = f2bf(v0.z); o[3] = f2bf(v0.w);
    o[4] = f2bf(v1.x); o[5] = f2bf(v1.y); o[6] = f2bf(v1.z); o[7] = f2bf(v1.w);
    *reinterpret_cast<us8*>(out + (size_t)i * 8) = o;
}

// ---------------------------------------------------------------------------
// fused prep: cvt x, W_in, W_out; pad+cvt W_x; A-table  (one launch)
// ---------------------------------------------------------------------------
#define PREP_X   524288
#define PREP_WI  (PREP_X + 524288)
#define PREP_WO  (PREP_WI + 262144)
#define PREP_WX  (PREP_WO + 12288)
#define PREP_A   (PREP_WX + 32768)
__global__ void prep_all(const float* __restrict__ x, const float* __restrict__ W_in,
                         const float* __restrict__ W_out, const float* __restrict__ wx,
                         const float* __restrict__ A_log,
                         unsigned short* __restrict__ Xb, unsigned short* __restrict__ W_inb,
                         unsigned short* __restrict__ W_outb, unsigned short* __restrict__ Wxb48,
                         float* __restrict__ At2) {
    int i = blockIdx.x * 256 + threadIdx.x;
    if (i < PREP_X) {
        cvt8_store(x, Xb, i);
    } else if (i < PREP_WI) {
        cvt8_store(W_in, W_inb, i - PREP_X);
    } else if (i < PREP_WO) {
        cvt8_store(W_out, W_outb, i - PREP_WI);
    } else if (i < PREP_WX) {
        int j = i - PREP_WO;
        size_t o = (size_t)j * 8;
        int row = (int)(o >> 11);
        if (row < 33) cvt8_store(wx, Wxb48, j);
        else *reinterpret_cast<us8*>(Wxb48 + o) = (us8)0;
    } else if (i < PREP_A) {
        int j = i - PREP_WX;            // j = n*DI + d
        int n = j / DI, d = j % DI;
        At2[j] = -__expf(A_log[d * DS + n]) * LOG2E;
    }
}

// ---------------------------------------------------------------------------
// GEMM1 (best measured variant, R9): 128x256 tile, 8 waves (2Mx4N, wave owns
// 64x64), BK=32, 2-deep LDS dbuf (48 KiB -> 2 blocks/CU, 16 waves/CU),
// XOR swizzle, setprio, bf16 out.  M=4096, N=4096, K=1024; grid 512.
// ---------------------------------------------------------------------------
#define NTK1 32
__global__ __launch_bounds__(512, 4)
void gemm1_2b(const unsigned short* __restrict__ A, const unsigned short* __restrict__ B,
              unsigned short* __restrict__ C) {
    __shared__ unsigned short As[2][128 * 32];   // 2 x 8 KiB
    __shared__ unsigned short Bs[2][256 * 32];   // 2 x 16 KiB

    const int tid = threadIdx.x;
    const int wid = tid >> 6, ln = tid & 63;
    const int wm = wid >> 2, wn = wid & 3;       // wave owns 64x64

    int wg = blockIdx.x;
    wg = (wg & 7) * 64 + (wg >> 3);              // XCD swizzle (512 % 8 == 0)
    const int m0 = (wg >> 4) * 128;
    const int n0 = (wg & 15) * 256;

    const int srow = tid >> 2;                   // 0..127
    const int sun  = tid & 3;
    const int ksrc = ((sun ^ ((srow >> 1) & 3)) * 8);  // same for srow and srow+128

    const int fr = ln & 15;
    const int fku = (ln >> 4);

    f32x4 acc[4][4] = {};

    #define STAGE1(kt, c)                                                                  \
        do {                                                                               \
            gload_lds16(A + (size_t)(m0 + srow) * 1024 + (kt) * 32 + ksrc,                 \
                        &As[c][srow * 32 + sun * 8]);                                      \
            gload_lds16(B + (size_t)(n0 + srow) * 1024 + (kt) * 32 + ksrc,                 \
                        &Bs[c][srow * 32 + sun * 8]);                                      \
            gload_lds16(B + (size_t)(n0 + 128 + srow) * 1024 + (kt) * 32 + ksrc,           \
                        &Bs[c][(128 + srow) * 32 + sun * 8]);                              \
        } while (0)

    STAGE1(0, 0);
    asm volatile("s_waitcnt vmcnt(0)" ::: "memory");
    __builtin_amdgcn_s_barrier();
    __builtin_amdgcn_sched_barrier(0);

    for (int kt = 0; kt < NTK1; ++kt) {
        const int c = kt & 1;
        if (kt + 1 < NTK1) STAGE1(kt + 1, c ^ 1);   // c^1 fully consumed before last barrier

        short8 af[4], bfr[4];
        #pragma unroll
        for (int i = 0; i < 4; ++i) {
            int r = wm * 64 + i * 16 + fr;
            int u = fku ^ ((r >> 1) & 3);
            af[i] = *reinterpret_cast<const short8*>(&As[c][r * 32 + u * 8]);
        }
        #pragma unroll
        for (int j = 0; j < 4; ++j) {
            int r = wn * 64 + j * 16 + fr;
            int u = fku ^ ((r >> 1) & 3);
            bfr[j] = *reinterpret_cast<const short8*>(&Bs[c][r * 32 + u * 8]);
        }
        __builtin_amdgcn_sched_barrier(0);
        __builtin_amdgcn_s_setprio(1);
        #pragma unroll
        for (int i = 0; i < 4; ++i)
            #pragma unroll
            for (int j = 0; j < 4; ++j)
                acc[i][j] = __builtin_amdgcn_mfma_f32_16x16x32_bf16(af[i], bfr[j], acc[i][j], 0, 0, 0);
        __builtin_amdgcn_s_setprio(0);
        __builtin_amdgcn_sched_barrier(0);

        if (kt + 1 < NTK1) asm volatile("s_waitcnt vmcnt(0)" ::: "memory");
        __builtin_amdgcn_s_barrier();
        __builtin_amdgcn_sched_barrier(0);
    }
    #undef STAGE1

    const int cr = (ln >> 4) * 4, cc = ln & 15;
    #pragma unroll
    for (int i = 0; i < 4; ++i) {
        int row = m0 + wm * 64 + i * 16 + cr;
        #pragma unroll
        for (int j = 0; j < 4; ++j) {
            int col = n0 + wn * 64 + j * 16 + cc;
            #pragma unroll
            for (int r = 0; r < 4; ++r)
                C[(size_t)(row + r) * 4096 + col] = f2bf(acc[i][j][r]);
        }
    }
}

// ---------------------------------------------------------------------------
// GEMM3: 128x64 tile, 4 waves (2x2), BK=32, 4-deep pipeline, counted vmcnt,
// k-unit XOR swizzle, f32 out.  A dense lda=2048.  grid 512.
// ---------------------------------------------------------------------------
#define NT3 64
__global__ __launch_bounds__(256, 2)
void gemm3_pipe(const unsigned short* __restrict__ A,
                const unsigned short* __restrict__ B,
                float* __restrict__ C) {
    __shared__ unsigned short As[4][128 * 32];   // 32 KiB
    __shared__ unsigned short Bs[4][64 * 32];    // 16 KiB

    const int tid = threadIdx.x;
    const int wid = tid >> 6, ln = tid & 63;
    const int wm = wid >> 1, wn = wid & 1;       // wave owns 64x32

    int wg = blockIdx.x;
    wg = (wg & 7) * 64 + (wg >> 3);              // XCD swizzle (512 % 8 == 0)
    const int m0 = (wg >> 4) * 128;
    const int n0 = (wg & 15) * 64;

    const int srow = tid >> 2;                   // 0..63
    const int sun  = tid & 3;
    const int ksrc = ((sun ^ ((srow >> 1) & 3)) * 8);

    const int fr = ln & 15;
    const int fku = (ln >> 4);

    f32x4 acc[4][2] = {};

    #define STAGE3(kt)                                                                     \
        do {                                                                               \
            const int bq_ = (kt) & 3;                                                      \
            gload_lds16(A + (size_t)(m0 + srow) * 2048 + (kt) * 32 + ksrc,                 \
                        &As[bq_][srow * 32 + sun * 8]);                                    \
            gload_lds16(A + (size_t)(m0 + 64 + srow) * 2048 + (kt) * 32 + ksrc,            \
                        &As[bq_][(64 + srow) * 32 + sun * 8]);                             \
            gload_lds16(B + (size_t)(n0 + srow) * 2048 + (kt) * 32 + ksrc,                 \
                        &Bs[bq_][srow * 32 + sun * 8]);                                    \
        } while (0)

    STAGE3(0); STAGE3(1); STAGE3(2);
    asm volatile("s_waitcnt vmcnt(6)" ::: "memory");   // K-tile 0 landed
    __builtin_amdgcn_s_barrier();
    __builtin_amdgcn_sched_barrier(0);

    for (int kt = 0; kt < NT3; ++kt) {
        const int bq = kt & 3;
        if (kt + 3 < NT3) STAGE3(kt + 3);

        short8 af[4], bfr[2];
        #pragma unroll
        for (int i = 0; i < 4; ++i) {
            int r = wm * 64 + i * 16 + fr;
            int u = fku ^ ((r >> 1) & 3);
            af[i] = *reinterpret_cast<const short8*>(&As[bq][r * 32 + u * 8]);
        }
        #pragma unroll
        for (int j = 0; j < 2; ++j) {
            int r = wn * 32 + j * 16 + fr;
            int u = fku ^ ((r >> 1) & 3);
            bfr[j] = *reinterpret_cast<const short8*>(&Bs[bq][r * 32 + u * 8]);
        }
        __builtin_amdgcn_sched_barrier(0);
        __builtin_amdgcn_s_setprio(1);
        #pragma unroll
        for (int i = 0; i < 4; ++i)
            #pragma unroll
            for (int j = 0; j < 2; ++j)
                acc[i][j] = __builtin_amdgcn_mfma_f32_16x16x32_bf16(af[i], bfr[j], acc[i][j], 0, 0, 0);
        __builtin_amdgcn_s_setprio(0);
        __builtin_amdgcn_sched_barrier(0);

        if (kt < NT3 - 3)       asm volatile("s_waitcnt vmcnt(6)" ::: "memory");
        else if (kt == NT3 - 3) asm volatile("s_waitcnt vmcnt(3)" ::: "memory");
        else if (kt == NT3 - 2) asm volatile("s_waitcnt vmcnt(0)" ::: "memory");
        __builtin_amdgcn_s_barrier();
        __builtin_amdgcn_sched_barrier(0);
    }
    #undef STAGE3

    const int cr = (ln >> 4) * 4, cc = ln & 15;
    #pragma unroll
    for (int i = 0; i < 4; ++i) {
        int row = m0 + wm * 64 + i * 16 + cr;
        #pragma unroll
        for (int j = 0; j < 2; ++j) {
            int col = n0 + wn * 32 + j * 16 + cc;
            #pragma unroll
            for (int r = 0; r < 4; ++r)
                C[(size_t)(row + r) * 1024 + col] = acc[i][j][r];
        }
    }
}

// ---------------------------------------------------------------------------
// FUSED conv+proj, K split 16 ways (grid (64,16) = 1024 blocks, 4 blocks/CU).
// ---------------------------------------------------------------------------
#define RAWS 40   // padded LDS row stride (elements)
__global__ __launch_bounds__(256)
void gemm_proj_conv(const unsigned short* __restrict__ XZb, const unsigned short* __restrict__ Wxb,
                    const float* __restrict__ cw, const float* __restrict__ cb,
                    float* __restrict__ projp) {
    __shared__ unsigned short raw[67 * RAWS];    // xz window rows m0-3..m0+63
    __shared__ unsigned short Bs[48 * 32];

    const int tid = threadIdx.x;
    const int wv = tid >> 6, ln = tid & 63;
    const int m0 = blockIdx.x * 64;
    const int kz = blockIdx.y;                   // 0..15
    const int srow = tid >> 2, skoff = (tid & 3) * 8;
    const int fr = ln & 15;
    const int lhat = wv * 16 + fr;               // output row 0..63
    const int d0 = (ln >> 4) * 8;                // fragment k-offset 0/8/16/24

    const bool mstart = ((m0 & 2047) == 0);      // block at batch start
    const int colbase = kz * 128;

    f32x4 acc[3] = {};

    for (int k0 = 0; k0 < 128; k0 += 32) {
        for (int j = tid; j < 268; j += 256) {
            int i = j >> 2, slot = j & 3;
            us8 v;
            if (mstart && i < 3) {
                v = (us8)0;
            } else {
                v = *reinterpret_cast<const us8*>(
                    XZb + (size_t)(m0 - 3 + i) * 4096 + colbase + k0 + slot * 8);
            }
            *reinterpret_cast<us8*>(&raw[i * RAWS + slot * 8]) = v;
        }
        if (wv < 3)
            gload_lds16(Wxb + (size_t)srow * 2048 + colbase + k0 + skoff, &Bs[wv * 512]);
        __syncthreads();

        short8 af;
        #pragma unroll
        for (int e = 0; e < 8; ++e) {
            int dg = colbase + k0 + d0 + e;
            float a = cb[dg];
            float4 w = *reinterpret_cast<const float4*>(cw + dg * 4);
            a += bf2f(raw[(lhat + 0) * RAWS + d0 + e]) * w.x;
            a += bf2f(raw[(lhat + 1) * RAWS + d0 + e]) * w.y;
            a += bf2f(raw[(lhat + 2) * RAWS + d0 + e]) * w.z;
            a += bf2f(raw[(lhat + 3) * RAWS + d0 + e]) * w.w;
            float v = a / (1.f + __expf(-a));
            ((unsigned short*)&af)[e] = (short)f2bf(v);
        }

        #pragma unroll
        for (int j = 0; j < 3; ++j) {
            short8 bf_ = *reinterpret_cast<const short8*>(&Bs[(j * 16 + fr) * 32 + d0]);
            acc[j] = __builtin_amdgcn_mfma_f32_16x16x32_bf16(af, bf_, acc[j], 0, 0, 0);
        }
        __syncthreads();
    }

    const int cr = (ln >> 4) * 4, cc = ln & 15;
    #pragma unroll
    for (int j = 0; j < 3; ++j) {
        int col = j * 16 + cc;
        if (col < 33) {
            #pragma unroll
            for (int r = 0; r < 4; ++r) {
                int row = m0 + wv * 16 + cr + r;
                projp[(size_t)row * 576 + kz * 36 + col] = acc[j][r];
            }
        }
    }
}

// combine 16 K-split partials -> dense PROJ[row*36+col]
__global__ void proj_combine(const float* __restrict__ projp, float* __restrict__ proj) {
    int idx = blockIdx.x * 256 + threadIdx.x;
    if (idx >= BATCH * LSEQ * 33) return;
    int row = idx / 33, col = idx % 33;
    const float* pp = projp + (size_t)row * 576 + col;
    float s = 0.f;
    #pragma unroll
    for (int kz = 0; kz < 16; ++kz)
        s += pp[kz * 36];
    proj[(size_t)row * 36 + col] = s;
}

// ---------------------------------------------------------------------------
// scan phase 1: local scan (h0=0) with in-register conv recompute from XZb.
// y_local + x*D (bf16), Hend (bf16), dtsum (f32).
// ---------------------------------------------------------------------------
__global__ __launch_bounds__(256)
void scan_phase1(const unsigned short* __restrict__ XZb, const float* __restrict__ proj,
                 const float* __restrict__ At2, const float* __restrict__ W_dt,
                 const float* __restrict__ b_dt, const float* __restrict__ Dp,
                 const float* __restrict__ cw, const float* __restrict__ cb,
                 unsigned short* __restrict__ Hend,
                 float* __restrict__ dtsum, unsigned short* __restrict__ yloc) {
    const int d = blockIdx.x * 256 + threadIdx.x;
    const int c = blockIdx.y;
    const int b = blockIdx.z;
    const size_t r0 = (size_t)(b * LSEQ + c * TCH);

    f32x2 A2[DS / 2], h2[DS / 2];
    #pragma unroll
    for (int p = 0; p < DS / 2; ++p) {
        A2[p] = (f32x2){At2[(2 * p) * DI + d], At2[(2 * p + 1) * DI + d]};
        h2[p] = (f32x2){0.f, 0.f};
    }
    const float wdt = W_dt[d], bdt = b_dt[d], Dv = Dp[d];
    const float4 w = *reinterpret_cast<const float4*>(cw + d * 4);
    const float cbv = cb[d];

    float r3, r2, r1;
    if (c == 0) {
        r3 = r2 = r1 = 0.f;
    } else {
        r3 = bf2f(XZb[(r0 - 3) * 4096 + d]);
        r2 = bf2f(XZb[(r0 - 2) * 4096 + d]);
        r1 = bf2f(XZb[(r0 - 1) * 4096 + d]);
    }
    float ssum = 0.f;

    #pragma unroll 2
    for (int rl = 0; rl < TCH; ++rl) {
        const size_t row = r0 + rl;
        const float* pr = proj + row * 36;
        float dt = softplus_f(pr[32] * wdt + bdt);
        ssum += dt;
        float rr = bf2f(XZb[row * 4096 + d]);
        float a = cbv + r3 * w.x + r2 * w.y + r1 * w.z + rr * w.w;
        r3 = r2; r2 = r1; r1 = rr;
        float v = a / (1.f + __expf(-a));
        float x = bf2f(f2bf(v));                 // match proj_conv's bf16 rounding
        float xdt = x * dt;
        f32x2 xdt2 = (f32x2){xdt, xdt};
        f32x2 y2 = (f32x2){0.f, 0.f};
        #pragma unroll
        for (int p = 0; p < DS / 2; ++p) {
            f32x2 t = A2[p] * dt;
            f32x2 e2 = (f32x2){fexp2(t.x), fexp2(t.y)};
            h2[p] = e2 * h2[p] + xdt2 * (f32x2){pr[2 * p], pr[2 * p + 1]};
            y2 += h2[p] * (f32x2){pr[16 + 2 * p], pr[17 + 2 * p]};
        }
        yloc[row * DI + d] = f2bf(y2.x + y2.y + x * Dv);   // x*D folded in
    }
    size_t base = ((size_t)(b * NC + c) * DS) * DI + d;
    #pragma unroll
    for (int p = 0; p < DS / 2; ++p) {
        Hend[base + (size_t)(2 * p) * DI]     = f2bf(h2[p].x);
        Hend[base + (size_t)(2 * p + 1) * DI] = f2bf(h2[p].y);
    }
    dtsum[(size_t)(b * NC + c) * DI + d] = ssum;
}

// ---------------------------------------------------------------------------
// scan phase 2: in-place chunk combine (bf16 H); Hend -> Hin  (serial,
// coalesced -- proven fastest; wave-parallel variant overfetched 4.4x)
// ---------------------------------------------------------------------------
__global__ void scan_phase2(unsigned short* __restrict__ H, const float* __restrict__ dtsum,
                            const float* __restrict__ At2) {
    int idx = blockIdx.x * 256 + threadIdx.x;
    int b = idx / (DS * DI);
    int r = idx % (DS * DI);
    int n = r / DI, d = r % DI;
    float A2 = At2[n * DI + d];
    float h = 0.f;
    #pragma unroll 4
    for (int c = 0; c < NC; ++c) {
        size_t off = ((size_t)(b * NC + c) * DS + n) * DI + d;
        float He = bf2f(H[off]);
        float P = fexp2(A2 * dtsum[(size_t)(b * NC + c) * DI + d]);
        H[off] = f2bf(h);
        h = P * h + He;
    }
}

// ---------------------------------------------------------------------------
// scan phase 3: parallel correction + gate; direct proj reads; recomputes
// dt/S in f32.  Writes y (bf16) densely into YB2.
// ---------------------------------------------------------------------------
__global__ __launch_bounds__(256)
void scan_phase3(const unsigned short* __restrict__ yloc,
                 const float* __restrict__ proj, const float* __restrict__ At2,
                 const float* __restrict__ W_dt, const float* __restrict__ b_dt,
                 const unsigned short* __restrict__ Hin,
                 const unsigned short* __restrict__ XZb,
                 unsigned short* __restrict__ YB2) {
    const int tid = threadIdx.x;
    const int d = blockIdx.x * 256 + tid;
    const int c = blockIdx.y;
    const int b = blockIdx.z;
    const size_t r0 = (size_t)(b * LSEQ + c * TCH);

    f32x2 A2[DS / 2], Hn2[DS / 2];
    size_t hbase = ((size_t)(b * NC + c) * DS) * DI + d;
    #pragma unroll
    for (int p = 0; p < DS / 2; ++p) {
        A2[p]  = (f32x2){At2[(2 * p) * DI + d], At2[(2 * p + 1) * DI + d]};
        Hn2[p] = (f32x2){bf2f(Hin[hbase + (size_t)(2 * p) * DI]),
                         bf2f(Hin[hbase + (size_t)(2 * p + 1) * DI])};
    }
    const float wdt = W_dt[d], bdt = b_dt[d];
    float S = 0.f;

    #pragma unroll 2
    for (int rl = 0; rl < TCH; ++rl) {
        const size_t row = r0 + rl;
        const float* pr = proj + row * 36;
        float dt = softplus_f(pr[32] * wdt + bdt);
        S += dt;
        float yl = bf2f(yloc[row * DI + d]);
        float z  = bf2f(XZb[row * 4096 + 2048 + d]);
        f32x2 corr2 = (f32x2){0.f, 0.f};
        #pragma unroll
        for (int p = 0; p < DS / 2; ++p) {
            f32x2 t = A2[p] * S;
            f32x2 e2 = (f32x2){fexp2(t.x), fexp2(t.y)};
            corr2 += (f32x2){pr[16 + 2 * p], pr[17 + 2 * p]} * e2 * Hn2[p];
        }
        float y = yl + corr2.x + corr2.y;
        float sz = z / (1.f + __expf(-z));
        YB2[row * DI + d] = f2bf(y * sz);
    }
}

// ---------------------------------------------------------------------------
extern "C" void kernel_launch(void* const* d_in, const int* in_sizes, int n_in,
                              void* d_out, int out_size, void* d_ws, size_t ws_size,
                              hipStream_t stream) {
    const float* x      = (const float*)d_in[0];
    const float* W_in   = (const float*)d_in[1];
    const float* conv_w = (const float*)d_in[2];
    const float* conv_b = (const float*)d_in[3];
    const float* W_x    = (const float*)d_in[4];
    const float* A_log  = (const float*)d_in[5];
    const float* Dp     = (const float*)d_in[6];
    const float* W_dt   = (const float*)d_in[7];
    const float* b_dt   = (const float*)d_in[8];
    const float* W_out  = (const float*)d_in[9];
    float* out = (float*)d_out;

    char* ws = (char*)d_ws;
    // workspace layout (bytes), ~112 MiB:
    unsigned short* XZb   = (unsigned short*)(ws + 0);           // 32 MiB  [t1..t6]
    float* PROJP = (float*)(ws + 33554432);                      // 9.4 MiB [t2..t2.5]
    unsigned short* Xb    = (unsigned short*)(ws + 50331648);    // 8 MiB   [t0..t1]
    unsigned short* W_inb = (unsigned short*)(ws + 58720256);    // 8 MiB   [t0..t1]
    unsigned short* YB2   = (unsigned short*)(ws + 50331648);    // 16 MiB  [t6..t7] over Xb+W_inb
    unsigned short* Hbuf  = (unsigned short*)(ws + 67108864);    // 16 MiB  [t4..t6]
    unsigned short* YLOC  = (unsigned short*)(ws + 83886080);    // 16 MiB  [t4..t6]
    float* PROJ  = (float*)(ws + 100663296);                     // 0.56 MiB [t2.5..t6]
    float* DTSUM = (float*)(ws + 101711872);                     // 2 MiB
    float* Abuf  = (float*)(ws + 106954752);                     // 128 KiB
    unsigned short* W_outb = (unsigned short*)(ws + 108003328);  // 4 MiB
    unsigned short* Wxb48  = (unsigned short*)(ws + 112197632);  // 192 KiB

    const int M = BATCH * LSEQ;   // 4096

    // t0) fused converts / prep (one launch)
    prep_all<<<(PREP_A + 255) / 256, 256, 0, stream>>>(
        x, W_in, W_out, W_x, A_log, Xb, W_inb, W_outb, Wxb48, Abuf);

    // t1) xz = x @ W_in.T -> bf16 XZb
    gemm1_2b<<<512, 512, 0, stream>>>(Xb, W_inb, XZb);

    // t2) fused conv+SiLU+proj (K split 16) -> PROJP; then dense combine
    gemm_proj_conv<<<dim3(M / 64, 16), 256, 0, stream>>>(
        XZb, Wxb48, conv_w, conv_b, PROJP);
    proj_combine<<<(M * 33 + 255) / 256, 256, 0, stream>>>(PROJP, PROJ);

    // t4-t6) chunked scan
    scan_phase1<<<dim3(DI / 256, NC, BATCH), 256, 0, stream>>>(
        XZb, PROJ, Abuf, W_dt, b_dt, Dp, conv_w, conv_b, Hbuf, DTSUM, YLOC);
    scan_phase2<<<BATCH * DS * DI / 256, 256, 0, stream>>>(Hbuf, DTSUM, Abuf);
    scan_phase3<<<dim3(DI / 256, NC, BATCH), 256, 0, stream>>>(
        YLOC, PROJ, Abuf, W_dt, b_dt, Hbuf, XZb, YB2);

    // t7) out = y @ W_out.T  (A = YB2 dense lda=2048)
    gemm3_pipe<<<512, 256, 0, stream>>>(YB2, W_outb, out);
}